// Round 11
// baseline (110.277 us; speedup 1.0000x reference)
//
#include <hip/hip_runtime.h>
#include <cstdint>
#include <cstddef>

#define NB 512
#define NL 32
#define KD 512     // P*D
#define KSLAB 256  // k-range per cost block
#define PASS 128   // k per staging pass

// swizzled float-offset of chunk ch (4 floats) of row `row` in a [32][128] pass buffer.
__device__ __forceinline__ int swz128(int row, int ch) {
  int csw = (ch & ~15) | ((ch ^ (row >> 1)) & 15);
  return row * PASS + csw * 4;
}

// ---------------- cost kernel: 1024 blocks x 256 thr, half-K per block ----------------
// R10 lesson: with grid <= resident capacity, kernel time = per-block serial
// latency. Halving per-block K halves that latency; the two K-slabs of a batch
// run on different CUs in parallel. 32 KB LDS -> 4 blocks/CU.
__global__ __launch_bounds__(256, 4)
void cost_kernel(const float* __restrict__ pred, const float* __restrict__ tgt,
                 float* __restrict__ cost_part) {
  __shared__ float smem[8192];   // 32 KB: predH[0..4096), tgtH[4096..8192); partials alias predH
  const int bid = blockIdx.x;
  const int b  = bid >> 1;
  const int ks = (bid & 1) * KSLAB;
  const int tid = threadIdx.x;
  float* predH = smem;
  float* tgtH  = smem + 4096;

  const int w = tid >> 6, l = tid & 63;   // 4 waves; wave w owns a 32-float k-slice/pass
  const int ti = l >> 3, tj = l & 7;      // 8x8 lanes of 4x4 output tiles
  float acc[4][4];
#pragma unroll
  for (int a = 0; a < 4; ++a)
#pragma unroll
    for (int c2 = 0; c2 < 4; ++c2) acc[a][c2] = 0.f;

  for (int hp = 0; hp < 2; ++hp) {
    __syncthreads();
    const size_t base = (size_t)b * (NL * KD) + ks + hp * PASS;
#pragma unroll
    for (int it = 0; it < 4; ++it) {
      int chunk = tid + it * 256;          // 0..1023 -> row, chunk-in-row (32x32 chunks)
      int row = chunk >> 5, ch = chunk & 31;
      const float4 pv = *reinterpret_cast<const float4*>(pred + base + (size_t)row * KD + ch * 4);
      const float4 tv = *reinterpret_cast<const float4*>(tgt  + base + (size_t)row * KD + ch * 4);
      int off = swz128(row, ch);
      *reinterpret_cast<float4*>(predH + off) = pv;
      *reinterpret_cast<float4*>(tgtH  + off) = tv;
    }
    __syncthreads();
#pragma unroll
    for (int c0 = 0; c0 < 8; ++c0) {
      const int c = (w << 3) + c0;         // wave's 8 chunks of this pass
      float4 pr[4], tg[4];
#pragma unroll
      for (int r = 0; r < 4; ++r) {
        pr[r] = *reinterpret_cast<const float4*>(predH + swz128(4 * ti + r, c));
        tg[r] = *reinterpret_cast<const float4*>(tgtH  + swz128(4 * tj + r, c));
      }
#pragma unroll
      for (int a = 0; a < 4; ++a)
#pragma unroll
        for (int c2 = 0; c2 < 4; ++c2) {
          float d;
          d = pr[a].x - tg[c2].x; acc[a][c2] += d * d;
          d = pr[a].y - tg[c2].y; acc[a][c2] += d * d;
          d = pr[a].z - tg[c2].z; acc[a][c2] += d * d;
          d = pr[a].w - tg[c2].w; acc[a][c2] += d * d;
        }
    }
  }
  __syncthreads();   // staging reads done; alias predH region with 4x1024 partials
  // disjoint bit-field layout: bank = (ti&3)+4*tj -> 2-way max (free)
#pragma unroll
  for (int a = 0; a < 4; ++a)
#pragma unroll
    for (int c2 = 0; c2 < 4; ++c2)
      smem[w * 1024 + (ti & 3) + 4 * tj + 32 * a + 128 * c2 + 512 * (ti >> 2)] = acc[a][c2];
  __syncthreads();
  const int ti2 = tid >> 5, a2 = (tid >> 3) & 3, tj2 = tid & 7;
  float ov[4];
#pragma unroll
  for (int k = 0; k < 4; ++k) {
    int ad = (ti2 & 3) + 4 * tj2 + 32 * a2 + 128 * k + 512 * (ti2 >> 2);
    ov[k] = (smem[ad] + smem[ad + 1024]) + (smem[ad + 2048] + smem[ad + 3072]);
  }
  float4 o4 = make_float4(ov[0], ov[1], ov[2], ov[3]);
  *reinterpret_cast<float4*>(cost_part + (size_t)bid * 1024 + tid * 4) = o4;
}

// ---------------- hungarian kernel: 512 blocks x 64 thr (R7-proven body) ----------------
__device__ __forceinline__ float readlane_f(float x, int lane) {
  return __int_as_float(__builtin_amdgcn_readlane(__float_as_int(x), lane));
}
__device__ __forceinline__ int readlane_i(int x, int lane) {
  return __builtin_amdgcn_readlane(x, lane);
}

template<int CTRL, int RM>
__device__ __forceinline__ float dppmin(float x) {
  int m = __builtin_amdgcn_update_dpp(__float_as_int(x), __float_as_int(x), CTRL, RM, 0xf, false);
  return fminf(x, __int_as_float(m));
}
// min over lanes 0..31, broadcast to all lanes via SGPR
__device__ __forceinline__ float wave_min32_bcast(float x) {
  x = dppmin<0xB1, 0xf>(x);   // quad_perm xor1
  x = dppmin<0x4E, 0xf>(x);   // quad_perm xor2
  x = dppmin<0x124, 0xf>(x);  // row_ror:4
  x = dppmin<0x128, 0xf>(x);  // row_ror:8 -> row16 min everywhere
  x = dppmin<0x142, 0xa>(x);  // row_bcast:15 -> lanes 16..31 = min(lanes 0..31)
  return readlane_f(x, 31);
}

__global__ __launch_bounds__(64)
void hung_kernel(const float* __restrict__ cost_part,
                 const float* __restrict__ prob,
                 const float* __restrict__ lmask,
                 const int* __restrict__ clf,
                 float* __restrict__ part) {
  __shared__ float cs[1024];    // cost[32][32]: row-select = 1 conflict-free ds_read_b32
  const int b = blockIdx.x;
  const int lane = threadIdx.x;

  // stage cost = sum of the batch's two K-slab partial planes
  {
    const float4* c0p = reinterpret_cast<const float4*>(cost_part + (size_t)(2 * b) * 1024);
    const float4* c1p = reinterpret_cast<const float4*>(cost_part + (size_t)(2 * b + 1) * 1024);
    float4* cs4 = reinterpret_cast<float4*>(cs);
#pragma unroll
    for (int k = 0; k < 4; ++k) {
      int i = lane + 64 * k;
      float4 x = c0p[i], y = c1p[i];
      cs4[i] = make_float4(x.x + y.x, x.y + y.y, x.z + y.z, x.w + y.w);
    }
  }

  float lm = (lane < 32) ? lmask[b * 32 + lane] : 0.f;
  const int n = __popcll(__ballot(lm > 0.5f));
  float clfpart = 0.f;
  if (lane < 32 && lm > 0.5f) {
    int cc = clf[b * 32 + lane];
    clfpart = -logf(prob[(size_t)(b * 32 + lane) * 2 + cc]);
  }
  __syncthreads();   // cs visible

  const float FINF = 1e30f;
  const bool activecol = (lane < n);
  const int cl = lane & 31;   // lanes 32..63 mirror -> same-addr broadcast (free)

  // Reference-faithful broken JV (minv/way never persisted in the python):
  // each step: fresh argmin over free cols of cost[i0][j]-u[i0]-v[j];
  // "augment" collapses to p[j_final] = ri. The uniform u[i0] doesn't affect
  // the argmin, so the min runs on key = c - v; delta = min(key) - u[i0].
  float u_r = 0.f, v_j = 0.f;
  int p_j = -1;

  for (int ri = 0; ri < n; ++ri) {
    int i0 = ri;
    bool usedc = false;
    bool usedr = (lane == ri);
    float rowv = cs[i0 * 32 + cl];
    while (true) {
      float key = rowv - v_j;                   // reduced cost (sans uniform u0)
      bool act = activecol && !usedc;
      float m = act ? key : FINF;
      float u0 = readlane_f(u_r, i0);           // off the min critical path
      float mn = wave_min32_bcast(m);
      uint64_t tie = __ballot(m == mn);
      int j1 = __ffsll((unsigned long long)tie) - 1;  // numpy first-index tie-break
      int pj1 = readlane_i(p_j, j1);
      int i0n = pj1 < 0 ? 0 : pj1;
      float rowv_n = cs[i0n * 32 + cl];         // speculative next-row read (pre-branch)
      float delta = mn - u0;
      if (usedr) u_r += delta;                  // u[p[used]] += delta
      if (usedc) v_j -= delta;                  // v[used]    -= delta
      if (pj1 < 0) {                            // free column -> p[j1] = ri, done
        if (lane == j1) p_j = ri;
        break;
      }
      usedc = usedc || (lane == j1);
      i0 = pj1;
      usedr = usedr || (lane == i0);
      rowv = rowv_n;
    }
  }

  // column j matched to row p[j] -> contributes cost[p[j]][j]
  int pj = p_j < 0 ? 0 : p_j;
  float a = activecol ? cs[pj * 32 + cl] : 0.f;
#pragma unroll
  for (int off = 32; off; off >>= 1) {
    a += __shfl_xor(a, off);
    clfpart += __shfl_xor(clfpart, off);
  }
  if (lane == 0) {
    part[b * 3 + 0] = a;
    part[b * 3 + 1] = clfpart;
    part[b * 3 + 2] = (float)n;
  }
}

// ---------------- finalize ----------------
__global__ void finalize_kernel(const float* __restrict__ part, float* __restrict__ out) {
  const int lane = threadIdx.x;   // 64 threads, 1 block: deterministic fixed-order reduce
  double cs = 0.0, ls = 0.0, ns = 0.0;
  for (int i = lane; i < NB; i += 64) {
    cs += (double)part[i * 3 + 0];
    ls += (double)part[i * 3 + 1];
    ns += (double)part[i * 3 + 2];
  }
#pragma unroll
  for (int off = 32; off; off >>= 1) {
    cs += __shfl_xor(cs, off);
    ls += __shfl_xor(ls, off);
    ns += __shfl_xor(ns, off);
  }
  if (lane == 0) {
    out[0] = (float)(cs / (ns * 256.0));  // / sum(point_masks) = 256 * sum(n)
    out[1] = (float)(ls / ns);            // / sum(line_masks)
  }
}

extern "C" void kernel_launch(void* const* d_in, const int* in_sizes, int n_in,
                              void* d_out, int out_size, void* d_ws, size_t ws_size,
                              hipStream_t stream) {
  const float* pred = (const float*)d_in[0];   // [512,32,256,2] f32
  const float* prob = (const float*)d_in[1];   // [512,32,2] f32
  const float* tgt  = (const float*)d_in[2];   // [512,32,256,2] f32
  const float* lm   = (const float*)d_in[3];   // [512,32] f32
  const int*   clf  = (const int*)d_in[4];     // [512,32] i32

  float* cost_part = (float*)d_ws;                       // 1024*1024 f32 = 4 MB
  float* part = cost_part + (size_t)1024 * 1024;         // 512*3 f32

  cost_kernel<<<NB * 2, 256, 0, stream>>>(pred, tgt, cost_part);
  hung_kernel<<<NB, 64, 0, stream>>>(cost_part, prob, lm, clf, part);
  finalize_kernel<<<1, 64, 0, stream>>>(part, (float*)d_out);
}

// Round 12
// 61.448 us; speedup vs baseline: 1.7946x; 1.7946x over previous
//
#include <hip/hip_runtime.h>
#include <cstdint>
#include <cstddef>

#define NB 512
#define NL 32
#define KD 512     // P*D
#define KSLAB 256  // k-range per cost block
#define PASS 128   // k per staging pass

// swizzled float-offset of chunk ch (4 floats) of row `row` in a [32][128] pass buffer.
__device__ __forceinline__ int swz128(int row, int ch) {
  int csw = (ch & ~15) | ((ch ^ (row >> 1)) & 15);
  return row * PASS + csw * 4;
}

// ---------------- cost kernel: 1024 blocks x 256 thr, half-K per block ----------------
// __launch_bounds__ 2nd arg: empirical VGPR cap = 256/arg2 on this toolchain
// ((256,2)->128, (512,2)->128, (512,4)->64, (256,4)->64). arg2=4 forced a
// 64-VGPR body -> ~500 B/thread scratch spill (R9: 143 MB, R11: 152 MB writes).
// arg2=2 gives cap 128 >= the ~116 the body needs; runtime occupancy is still
// 4 blocks/CU (VGPR 116 -> 4 waves/EU; LDS 32 KB -> 5 blocks/CU).
__global__ __launch_bounds__(256, 2)
void cost_kernel(const float* __restrict__ pred, const float* __restrict__ tgt,
                 float* __restrict__ cost_part) {
  __shared__ float smem[8192];   // 32 KB: predH[0..4096), tgtH[4096..8192); partials alias predH
  const int bid = blockIdx.x;
  const int b  = bid >> 1;
  const int ks = (bid & 1) * KSLAB;
  const int tid = threadIdx.x;
  float* predH = smem;
  float* tgtH  = smem + 4096;

  const int w = tid >> 6, l = tid & 63;   // 4 waves; wave w owns a 32-float k-slice/pass
  const int ti = l >> 3, tj = l & 7;      // 8x8 lanes of 4x4 output tiles
  float acc[4][4];
#pragma unroll
  for (int a = 0; a < 4; ++a)
#pragma unroll
    for (int c2 = 0; c2 < 4; ++c2) acc[a][c2] = 0.f;

  for (int hp = 0; hp < 2; ++hp) {
    __syncthreads();
    const size_t base = (size_t)b * (NL * KD) + ks + hp * PASS;
#pragma unroll
    for (int it = 0; it < 4; ++it) {
      int chunk = tid + it * 256;          // 0..1023 -> row, chunk-in-row (32x32 chunks)
      int row = chunk >> 5, ch = chunk & 31;
      const float4 pv = *reinterpret_cast<const float4*>(pred + base + (size_t)row * KD + ch * 4);
      const float4 tv = *reinterpret_cast<const float4*>(tgt  + base + (size_t)row * KD + ch * 4);
      int off = swz128(row, ch);
      *reinterpret_cast<float4*>(predH + off) = pv;
      *reinterpret_cast<float4*>(tgtH  + off) = tv;
    }
    __syncthreads();
#pragma unroll
    for (int c0 = 0; c0 < 8; ++c0) {
      const int c = (w << 3) + c0;         // wave's 8 chunks of this pass
      float4 pr[4], tg[4];
#pragma unroll
      for (int r = 0; r < 4; ++r) {
        pr[r] = *reinterpret_cast<const float4*>(predH + swz128(4 * ti + r, c));
        tg[r] = *reinterpret_cast<const float4*>(tgtH  + swz128(4 * tj + r, c));
      }
#pragma unroll
      for (int a = 0; a < 4; ++a)
#pragma unroll
        for (int c2 = 0; c2 < 4; ++c2) {
          float d;
          d = pr[a].x - tg[c2].x; acc[a][c2] += d * d;
          d = pr[a].y - tg[c2].y; acc[a][c2] += d * d;
          d = pr[a].z - tg[c2].z; acc[a][c2] += d * d;
          d = pr[a].w - tg[c2].w; acc[a][c2] += d * d;
        }
    }
  }
  __syncthreads();   // staging reads done; alias predH region with 4x1024 partials
  // disjoint bit-field layout: bank = (ti&3)+4*tj -> 2-way max (free)
#pragma unroll
  for (int a = 0; a < 4; ++a)
#pragma unroll
    for (int c2 = 0; c2 < 4; ++c2)
      smem[w * 1024 + (ti & 3) + 4 * tj + 32 * a + 128 * c2 + 512 * (ti >> 2)] = acc[a][c2];
  __syncthreads();
  const int ti2 = tid >> 5, a2 = (tid >> 3) & 3, tj2 = tid & 7;
  float ov[4];
#pragma unroll
  for (int k = 0; k < 4; ++k) {
    int ad = (ti2 & 3) + 4 * tj2 + 32 * a2 + 128 * k + 512 * (ti2 >> 2);
    ov[k] = (smem[ad] + smem[ad + 1024]) + (smem[ad + 2048] + smem[ad + 3072]);
  }
  float4 o4 = make_float4(ov[0], ov[1], ov[2], ov[3]);
  *reinterpret_cast<float4*>(cost_part + (size_t)bid * 1024 + tid * 4) = o4;
}

// ---------------- hungarian kernel: 512 blocks x 64 thr (R7-proven body) ----------------
__device__ __forceinline__ float readlane_f(float x, int lane) {
  return __int_as_float(__builtin_amdgcn_readlane(__float_as_int(x), lane));
}
__device__ __forceinline__ int readlane_i(int x, int lane) {
  return __builtin_amdgcn_readlane(x, lane);
}

template<int CTRL, int RM>
__device__ __forceinline__ float dppmin(float x) {
  int m = __builtin_amdgcn_update_dpp(__float_as_int(x), __float_as_int(x), CTRL, RM, 0xf, false);
  return fminf(x, __int_as_float(m));
}
// min over lanes 0..31, broadcast to all lanes via SGPR
__device__ __forceinline__ float wave_min32_bcast(float x) {
  x = dppmin<0xB1, 0xf>(x);   // quad_perm xor1
  x = dppmin<0x4E, 0xf>(x);   // quad_perm xor2
  x = dppmin<0x124, 0xf>(x);  // row_ror:4
  x = dppmin<0x128, 0xf>(x);  // row_ror:8 -> row16 min everywhere
  x = dppmin<0x142, 0xa>(x);  // row_bcast:15 -> lanes 16..31 = min(lanes 0..31)
  return readlane_f(x, 31);
}

__global__ __launch_bounds__(64)
void hung_kernel(const float* __restrict__ cost_part,
                 const float* __restrict__ prob,
                 const float* __restrict__ lmask,
                 const int* __restrict__ clf,
                 float* __restrict__ part) {
  __shared__ float cs[1024];    // cost[32][32]: row-select = 1 conflict-free ds_read_b32
  const int b = blockIdx.x;
  const int lane = threadIdx.x;

  // stage cost = sum of the batch's two K-slab partial planes
  {
    const float4* c0p = reinterpret_cast<const float4*>(cost_part + (size_t)(2 * b) * 1024);
    const float4* c1p = reinterpret_cast<const float4*>(cost_part + (size_t)(2 * b + 1) * 1024);
    float4* cs4 = reinterpret_cast<float4*>(cs);
#pragma unroll
    for (int k = 0; k < 4; ++k) {
      int i = lane + 64 * k;
      float4 x = c0p[i], y = c1p[i];
      cs4[i] = make_float4(x.x + y.x, x.y + y.y, x.z + y.z, x.w + y.w);
    }
  }

  float lm = (lane < 32) ? lmask[b * 32 + lane] : 0.f;
  const int n = __popcll(__ballot(lm > 0.5f));
  float clfpart = 0.f;
  if (lane < 32 && lm > 0.5f) {
    int cc = clf[b * 32 + lane];
    clfpart = -logf(prob[(size_t)(b * 32 + lane) * 2 + cc]);
  }
  __syncthreads();   // cs visible

  const float FINF = 1e30f;
  const bool activecol = (lane < n);
  const int cl = lane & 31;   // lanes 32..63 mirror -> same-addr broadcast (free)

  // Reference-faithful broken JV (minv/way never persisted in the python):
  // each step: fresh argmin over free cols of cost[i0][j]-u[i0]-v[j];
  // "augment" collapses to p[j_final] = ri. The uniform u[i0] doesn't affect
  // the argmin, so the min runs on key = c - v; delta = min(key) - u[i0].
  float u_r = 0.f, v_j = 0.f;
  int p_j = -1;

  for (int ri = 0; ri < n; ++ri) {
    int i0 = ri;
    bool usedc = false;
    bool usedr = (lane == ri);
    float rowv = cs[i0 * 32 + cl];
    while (true) {
      float key = rowv - v_j;                   // reduced cost (sans uniform u0)
      bool act = activecol && !usedc;
      float m = act ? key : FINF;
      float u0 = readlane_f(u_r, i0);           // off the min critical path
      float mn = wave_min32_bcast(m);
      uint64_t tie = __ballot(m == mn);
      int j1 = __ffsll((unsigned long long)tie) - 1;  // numpy first-index tie-break
      int pj1 = readlane_i(p_j, j1);
      int i0n = pj1 < 0 ? 0 : pj1;
      float rowv_n = cs[i0n * 32 + cl];         // speculative next-row read (pre-branch)
      float delta = mn - u0;
      if (usedr) u_r += delta;                  // u[p[used]] += delta
      if (usedc) v_j -= delta;                  // v[used]    -= delta
      if (pj1 < 0) {                            // free column -> p[j1] = ri, done
        if (lane == j1) p_j = ri;
        break;
      }
      usedc = usedc || (lane == j1);
      i0 = pj1;
      usedr = usedr || (lane == i0);
      rowv = rowv_n;
    }
  }

  // column j matched to row p[j] -> contributes cost[p[j]][j]
  int pj = p_j < 0 ? 0 : p_j;
  float a = activecol ? cs[pj * 32 + cl] : 0.f;
#pragma unroll
  for (int off = 32; off; off >>= 1) {
    a += __shfl_xor(a, off);
    clfpart += __shfl_xor(clfpart, off);
  }
  if (lane == 0) {
    part[b * 3 + 0] = a;
    part[b * 3 + 1] = clfpart;
    part[b * 3 + 2] = (float)n;
  }
}

// ---------------- finalize ----------------
__global__ void finalize_kernel(const float* __restrict__ part, float* __restrict__ out) {
  const int lane = threadIdx.x;   // 64 threads, 1 block: deterministic fixed-order reduce
  double cs = 0.0, ls = 0.0, ns = 0.0;
  for (int i = lane; i < NB; i += 64) {
    cs += (double)part[i * 3 + 0];
    ls += (double)part[i * 3 + 1];
    ns += (double)part[i * 3 + 2];
  }
#pragma unroll
  for (int off = 32; off; off >>= 1) {
    cs += __shfl_xor(cs, off);
    ls += __shfl_xor(ls, off);
    ns += __shfl_xor(ns, off);
  }
  if (lane == 0) {
    out[0] = (float)(cs / (ns * 256.0));  // / sum(point_masks) = 256 * sum(n)
    out[1] = (float)(ls / ns);            // / sum(line_masks)
  }
}

extern "C" void kernel_launch(void* const* d_in, const int* in_sizes, int n_in,
                              void* d_out, int out_size, void* d_ws, size_t ws_size,
                              hipStream_t stream) {
  const float* pred = (const float*)d_in[0];   // [512,32,256,2] f32
  const float* prob = (const float*)d_in[1];   // [512,32,2] f32
  const float* tgt  = (const float*)d_in[2];   // [512,32,256,2] f32
  const float* lm   = (const float*)d_in[3];   // [512,32] f32
  const int*   clf  = (const int*)d_in[4];     // [512,32] i32

  float* cost_part = (float*)d_ws;                       // 1024*1024 f32 = 4 MB
  float* part = cost_part + (size_t)1024 * 1024;         // 512*3 f32

  cost_kernel<<<NB * 2, 256, 0, stream>>>(pred, tgt, cost_part);
  hung_kernel<<<NB, 64, 0, stream>>>(cost_part, prob, lm, clf, part);
  finalize_kernel<<<1, 64, 0, stream>>>(part, (float*)d_out);
}